// Round 4
// baseline (224.401 us; speedup 1.0000x reference)
//
#include <hip/hip_runtime.h>
#include <math.h>

#define N 8192
#define M 8192
#define KEEP 4096

// ws: [0, 64KB) K64 array: (bits(imp)<<32)|idx  (u64, one per query)
// out layout (floats):
//   [0,16384) coords | [16384,98304) voxels | [98304,102400) kept_imp
//   [102400,110592) importance

// ---------------------------------------------------------------- importance
// One kernel: pass1 (masked max), pass2 (exp near max), MLP, K64 build.
// block = 64 queries (lane) x 16 key-slices (wave). Keys are read at
// wave-uniform addresses -> scalar loads (s_load_dwordx4) feeding VALU via
// SGPRs: no LDS, no vector-memory in the inner loops.
__global__ __launch_bounds__(1024) void importance_kernel(
    const int4*   __restrict__ vcoords,   // N x 4 [b,z,y,x]
    const float4* __restrict__ kcoords,   // M x 4 [b,z,y,x]
    const float*  __restrict__ w1, const float* __restrict__ b1,
    const float*  __restrict__ w2, const float* __restrict__ b2,
    float* __restrict__ out_imp,          // N (d_out + 102400)
    unsigned long long* __restrict__ Kout)// N (ws)
{
    __shared__ float red[5][16][64];      // 20 KB

    const int t = threadIdx.x, w = t >> 6, lane = t & 63;
    const int qi = blockIdx.x * 64 + lane;

    const int4 vc = vcoords[qi];
    const float qb = (float)vc.x;
    const float qz = (float)vc.y;
    const float qy = (float)vc.z;
    const float qx = (float)vc.w;
    const float inv_sqrt3 = 0.57735026918962576f;

    const int jb = w * 512, je = jb + 512;

    // ---- pass 1: masked max of dot ----
    // dm = dot - |k.x - qb|*1e10: matched -> fma(0,-1e10,dot) == dot EXACTLY;
    // mismatched -> ~ -1e10, can never win (dot <= ~4.2e6, cutoff >= -156).
    float mx = -INFINITY;
    #pragma unroll 8
    for (int j = jb; j < je; ++j) {
        float4 k4 = kcoords[j];
        float dot = fmaf(qz, k4.y, fmaf(qy, k4.z, qx * k4.w));
        float d   = k4.x - qb;
        float dm  = fmaf(fabsf(d), -1e10f, dot);
        mx = fmaxf(mx, dm);
    }
    red[0][w][lane] = mx;
    __syncthreads();
    #pragma unroll
    for (int i = 0; i < 16; ++i) mx = fmaxf(mx, red[0][i][lane]);

    // ---- pass 2: exp only near the max (same cutoff as rounds 2/3) ----
    const float cutoff = mx - 155.8845727f;
    float l = 0.f, szz = 0.f, syy = 0.f, sxx = 0.f;
    #pragma unroll 4
    for (int j = jb; j < je; ++j) {
        float4 k4 = kcoords[j];
        float dot = fmaf(qz, k4.y, fmaf(qy, k4.z, qx * k4.w));
        float d   = k4.x - qb;
        float dm  = fmaf(fabsf(d), -1e10f, dot);
        bool take = (dm >= cutoff);
        if (__any(take)) {
            float e = take ? expf((dm - mx) * inv_sqrt3) : 0.f;
            l  += e;
            szz = fmaf(e, k4.y, szz);
            syy = fmaf(e, k4.z, syy);
            sxx = fmaf(e, k4.w, sxx);
        }
    }
    red[1][w][lane] = l;
    red[2][w][lane] = szz;
    red[3][w][lane] = syy;
    red[4][w][lane] = sxx;
    __syncthreads();

    if (w == 0) {
        // deterministic fold in ascending slice order (j-ascending grouping)
        float L = 0.f, SZ = 0.f, SY = 0.f, SX = 0.f;
        #pragma unroll
        for (int i = 0; i < 16; ++i) {
            L  += red[1][i][lane];
            SZ += red[2][i][lane];
            SY += red[3][i][lane];
            SX += red[4][i][lane];
        }
        float inv = (L > 0.f) ? 1.f / L : 0.f;
        float cz = SZ * inv, cy = SY * inv, cx = SX * inv;
        float logit = b2[0];
        #pragma unroll
        for (int k = 0; k < 32; ++k) {
            float h = b1[k] + cz * w1[k] + cy * w1[32 + k] + cx * w1[64 + k];
            h = fmaxf(h, 0.f);
            logit += h * w2[k];
        }
        float p = 1.f / (1.f + expf(-logit));
        out_imp[qi] = p;
        Kout[qi] = ((unsigned long long)__float_as_uint(p) << 32) | (unsigned)qi;
    }
}

// ------------------------------------------------------------- rank+scatter
// rank(i) = #{j: K_j < K_i} == stable argsort rank (idx in low bits).
// Ballot transpose: lane = j (1024 j's per wave in 16 VGPRs), i broadcast via
// readlane -> per 64 pairs: one v_cmp_lt_u64 + scalar popcount. No LDS reads
// in the hot loop. Block = 64 i's x 16 j-slices; fold + scatter in wave 0.
__global__ __launch_bounds__(1024) void rank_scatter_kernel(
    const unsigned long long* __restrict__ K,   // N (ws)
    const int4*  __restrict__ vcoords,
    const float* __restrict__ voxels,
    float* __restrict__ out)
{
    __shared__ int scnt[16][64];          // 4 KB
    const int t = threadIdx.x, w = t >> 6, lane = t & 63;
    const int ibase = blockIdx.x * 64;

    // my i-element (broadcast source)
    const unsigned long long KiV = K[ibase + lane];
    const int kiLo = (int)(unsigned)KiV;
    const int kiHi = (int)(unsigned)(KiV >> 32);

    // my j-slice: 512 elements in 8 u64 registers
    const int jbase = w * 512;
    unsigned long long kj[8];
    #pragma unroll
    for (int r = 0; r < 8; ++r) kj[r] = K[jbase + r * 64 + lane];

    int acc = 0;                          // lane l holds count for i = ibase+l
    for (int i = 0; i < 64; ++i) {
        unsigned lo = (unsigned)__builtin_amdgcn_readlane(kiLo, i);
        unsigned hi = (unsigned)__builtin_amdgcn_readlane(kiHi, i);
        unsigned long long ki = ((unsigned long long)hi << 32) | lo;
        int c = 0;
        #pragma unroll
        for (int r = 0; r < 8; ++r)
            c += (int)__popcll(__ballot(kj[r] < ki));
        acc = (lane == i) ? c : acc;
    }
    scnt[w][lane] = acc;
    __syncthreads();

    if (w == 0) {
        int rank = 0;
        #pragma unroll
        for (int i = 0; i < 16; ++i) rank += scnt[i][lane];
        if (rank >= KEEP) {
            const int p = rank - KEEP;
            const int i = ibase + lane;
            int4 vc = vcoords[i];
            float4 c4;
            c4.x = (float)vc.x; c4.y = (float)vc.y;
            c4.z = (float)vc.z; c4.w = (float)vc.w;
            *(float4*)(out + p * 4) = c4;
            const float4* vs = (const float4*)(voxels + i * 20);
            float4* vd = (float4*)(out + 16384 + p * 20);
            #pragma unroll
            for (int k = 0; k < 5; ++k) vd[k] = vs[k];
            out[98304 + p] = __uint_as_float((unsigned)(KiV >> 32));
        }
    }
}

extern "C" void kernel_launch(void* const* d_in, const int* in_sizes, int n_in,
                              void* d_out, int out_size, void* d_ws, size_t ws_size,
                              hipStream_t stream) {
    const int4*   vcoords = (const int4*)d_in[0];
    const float4* kcoords = (const float4*)d_in[1];
    const float*  voxels  = (const float*)d_in[2];
    const float*  w1      = (const float*)d_in[3];
    const float*  b1      = (const float*)d_in[4];
    const float*  w2      = (const float*)d_in[5];
    const float*  b2      = (const float*)d_in[6];
    float* out = (float*)d_out;
    unsigned long long* K64 = (unsigned long long*)d_ws;

    importance_kernel<<<N / 64, 1024, 0, stream>>>(vcoords, kcoords, w1, b1, w2, b2,
                                                   out + 102400, K64);
    rank_scatter_kernel<<<N / 64, 1024, 0, stream>>>(K64, vcoords, voxels, out);
}